// Round 6
// baseline (549.309 us; speedup 1.0000x reference)
//
#include <hip/hip_runtime.h>

#define EPSF 1e-8f
#define RCUT 4.8f
#define NB 64
#define NSEL 20

__device__ __forceinline__ float fast_tanh(float x) {
    float e = __expf(2.0f * x);
    return 1.0f - __fdividef(2.0f, e + 1.0f);
}

// ---------------- Kernel A: norms + select 20 nearest (sorted) ----------------
extern "C" __global__ void __launch_bounds__(256)
sel_kernel(const float* __restrict__ dr, const float* __restrict__ W0,
           float* __restrict__ ws_R, float* __restrict__ ws_fc,
           float* __restrict__ ws_F, int* __restrict__ ws_idx,
           float* __restrict__ ws_ndn, float* __restrict__ ws_W0T)
{
    __shared__ float R_s[256];
    const int t = threadIdx.x;
    const int g = t >> 6;       // which b within block (0..3)
    const int j = t & 63;       // neighbor id
    const int b = blockIdx.x * 4 + g;

    const float* p = dr + ((size_t)b * NB + j) * 3;
    float x = p[0] + EPSF, y = p[1] + EPSF, z = p[2] + EPSF;
    float R = sqrtf(x * x + y * y + z * z);
    R_s[t] = R;
    __syncthreads();

    // stable rank: count (Rk < R) or (Rk == R and k < j)
    int rank = 0;
    const float* grp = R_s + g * 64;
    #pragma unroll 8
    for (int k = 0; k < 64; ++k) {
        float Rk = grp[k];
        rank += (Rk < R || (Rk == R && k < j)) ? 1 : 0;
    }

    float fc = 0.0f;
    if (rank < NSEL) {
        fc = (R > RCUT) ? 0.0f
                        : (0.5f * __cosf(3.14159265358979323846f * R / RCUT) + 0.5f);
        size_t o = (size_t)b * NSEL + rank;
        ws_R[o]  = R;
        ws_fc[o] = fc;
        ws_idx[o] = j;
        float inv = 1.0f / R;
        ws_ndn[o * 3 + 0] = x * inv;
        ws_ndn[o * 3 + 1] = y * inv;
        ws_ndn[o * 3 + 2] = z * inv;
    }

    // F[b] = sum of selected fc over this wave (each group is exactly one wave)
    float F = fc;
    for (int off = 32; off > 0; off >>= 1) F += __shfl_xor(F, off, 64);
    if (j == 0) ws_F[b] = F;

    // one-time W0 transpose (block 0 only; A always runs before B on the stream)
    if (blockIdx.x == 0) {
        for (int i = t; i < 15 * 64; i += 256) {
            int k = i >> 6, jj = i & 63;
            ws_W0T[jj * 15 + k] = W0[i];
        }
    }
}

// ---------------- Kernel B: per-pair MLP fwd + analytic bwd ----------------
// (320,4): target 128 total regs/wave (64 AGPR acc + <=64 arch) -> 4 waves/SIMD.
// R5 ran ~192 regs (2 waves/SIMD, VALUBusy 46%): acc's h2->dz2 live range
// crossed a __syncthreads (likely forcing a 64-reg clone) and the bwd loop
// held two W0 rows. Fix: single barrier AFTER backward; bwd loop single-j.
extern "C" __global__ void __launch_bounds__(320, 4)
energy_kernel(const float* __restrict__ orientation, const float* __restrict__ n_or,
              const float* __restrict__ W0T, const float* __restrict__ b0,
              const float* __restrict__ W1, const float* __restrict__ b1,
              const float* __restrict__ W2, const float* __restrict__ b2v,
              const float* __restrict__ f1, const float* __restrict__ f2,
              const float* __restrict__ ws_R, const float* __restrict__ ws_fc,
              const float* __restrict__ ws_F, const int* __restrict__ ws_idx,
              const float* __restrict__ ws_ndn,
              float* __restrict__ out_force, float* __restrict__ out_torque,
              float* __restrict__ out_energy)
{
    __shared__ float p_s[320];
    __shared__ float red[320][12];
    __shared__ float G[16][12];

    const int t = threadIdx.x;
    const int bl = t / 20;      // local b (0..15)
    const int n  = t % 20;      // selected-neighbor slot
    const int b  = blockIdx.x * 16 + bl;
    const size_t o = (size_t)b * NSEL + n;

    // feat = [dr_o(3), dr_no(3), o_no(9)]; O/Nr/nd scoped so they die here.
    float feat[15];
    {
        const float nd0 = ws_ndn[o * 3 + 0];
        const float nd1 = ws_ndn[o * 3 + 1];
        const float nd2 = ws_ndn[o * 3 + 2];
        const int  idx = ws_idx[o];
        float O[9], Nr[9];
        const float* Op = orientation + (size_t)b * 9;
        #pragma unroll
        for (int i = 0; i < 9; ++i) O[i] = Op[i];
        const float* Np = n_or + ((size_t)b * NB + idx) * 9;
        #pragma unroll
        for (int i = 0; i < 9; ++i) Nr[i] = Np[i];

        #pragma unroll
        for (int h = 0; h < 3; ++h)
            feat[h] = nd0 * O[h] + nd1 * O[3 + h] + nd2 * O[6 + h];
        #pragma unroll
        for (int h = 0; h < 3; ++h)
            feat[3 + h] = nd0 * Nr[h] + nd1 * Nr[3 + h] + nd2 * Nr[6 + h];
        #pragma unroll
        for (int l = 0; l < 3; ++l)
            #pragma unroll
            for (int m = 0; m < 3; ++m)
                feat[6 + l * 3 + m] = O[l] * Nr[m] + O[3 + l] * Nr[3 + m] + O[6 + l] * Nr[6 + m];
    }

    // ---------- forward (j, j+1 interleaved for 2x ILP on the serial chain) ----
    float acc[64];                      // z2 accumulators -> h2 -> dz2 (in place)
    #pragma unroll
    for (int i = 0; i < 64; ++i) acc[i] = b1[i];

    for (int j = 0; j < 64; j += 2) {
        const float* w0a = W0T + j * 15;
        const float* w0b = w0a + 15;
        float za = b0[j], zb = b0[j + 1];
        #pragma unroll
        for (int k = 0; k < 15; ++k) {
            za = fmaf(feat[k], w0a[k], za);
            zb = fmaf(feat[k], w0b[k], zb);
        }
        float ha = fast_tanh(za), hb = fast_tanh(zb);
        const float* w1a = W1 + j * 64;
        const float* w1b = w1a + 64;
        #pragma unroll
        for (int i = 0; i < 64; ++i)
            acc[i] = fmaf(hb, w1b[i], fmaf(ha, w1a[i], acc[i]));
    }

    // ---------- h2, z3 (4 partial sums) ----------
    float z30 = b2v[0], z31 = 0.f, z32 = 0.f, z33 = 0.f;
    #pragma unroll
    for (int i = 0; i < 64; i += 4) {
        acc[i]     = fast_tanh(acc[i]);
        acc[i + 1] = fast_tanh(acc[i + 1]);
        acc[i + 2] = fast_tanh(acc[i + 2]);
        acc[i + 3] = fast_tanh(acc[i + 3]);
        z30 = fmaf(acc[i],     W2[i],     z30);
        z31 = fmaf(acc[i + 1], W2[i + 1], z31);
        z32 = fmaf(acc[i + 2], W2[i + 2], z32);
        z33 = fmaf(acc[i + 3], W2[i + 3], z33);
    }
    const float enc = fast_tanh((z30 + z31) + (z32 + z33));
    float x;
    {
        const volatile float* Rv = ws_R + o;    // late load: don't hold R
        x = Rv[0] - (enc * enc + EPSF);
    }

    const float lx = __logf(x);
    float psum = 0.f, csum = 0.f;
    #pragma unroll
    for (int q = 0; q < 3; ++q) {
        float aq = f1[q] * f1[q] + EPSF;
        float cq = f2[q] * f2[q] + EPSF;
        float tq = __expf(-cq * (__logf(aq) + lx));   // (a*x)^(-c)
        psum += tq;
        csum = fmaf(cq, tq, csum);
    }
    const float dpdx = -__fdividef(csum, x);

    // ---------- backward (no barrier until all register work is done) --------
    float dz3;
    {
        const volatile float* Fv = ws_F + b;    // late load: don't hold F
        dz3 = Fv[0] * dpdx * (-2.f * enc) * (1.f - enc * enc);
    }
    #pragma unroll
    for (int i = 0; i < 64; ++i) {
        float h2 = acc[i];
        acc[i] = dz3 * W2[i] * (1.f - h2 * h2);   // dz2 (in place, no barrier crossed)
    }

    float dfeat[15];
    #pragma unroll
    for (int k = 0; k < 15; ++k) dfeat[k] = 0.f;

    for (int j = 0; j < 64; ++j) {              // single-j: one W0 row in flight
        const float* w1r = W1 + j * 64;
        float s0 = 0.f, s1 = 0.f, s2 = 0.f, s3 = 0.f;
        #pragma unroll
        for (int i = 0; i < 64; i += 4) {
            s0 = fmaf(acc[i],     w1r[i],     s0);
            s1 = fmaf(acc[i + 1], w1r[i + 1], s1);
            s2 = fmaf(acc[i + 2], w1r[i + 2], s2);
            s3 = fmaf(acc[i + 3], w1r[i + 3], s3);
        }
        float dh1 = (s0 + s1) + (s2 + s3);
        const float* w0r = W0T + j * 15;
        float z1 = b0[j];                        // recompute h1
        #pragma unroll
        for (int k = 0; k < 15; ++k) z1 = fmaf(feat[k], w0r[k], z1);
        float h1 = fast_tanh(z1);
        float dz1 = dh1 * (1.f - h1 * h1);
        #pragma unroll
        for (int k = 0; k < 15; ++k) dfeat[k] = fmaf(dz1, w0r[k], dfeat[k]);
    }

    // ---- per-pair gradients (reload O/Nr/nd volatile; short live ranges) ----
    float gdr[3], gO[9];
    {
        float O[9], Nr[9], nd0, nd1, nd2;
        {
            const volatile int* iv = ws_idx + o;
            const int idx = iv[0];
            const volatile float* Ov = orientation + (size_t)b * 9;
            const volatile float* Nv = n_or + ((size_t)b * NB + idx) * 9;
            #pragma unroll
            for (int i = 0; i < 9; ++i) O[i] = Ov[i];
            #pragma unroll
            for (int i = 0; i < 9; ++i) Nr[i] = Nv[i];
            const volatile float* nv = ws_ndn + o * 3;
            nd0 = nv[0]; nd1 = nv[1]; nd2 = nv[2];
        }

        #pragma unroll
        for (int k = 0; k < 3; ++k)
            gdr[k] = dfeat[0] * O[k * 3] + dfeat[1] * O[k * 3 + 1] + dfeat[2] * O[k * 3 + 2]
                   + dfeat[3] * Nr[k * 3] + dfeat[4] * Nr[k * 3 + 1] + dfeat[5] * Nr[k * 3 + 2];

        float ndv[3] = {nd0, nd1, nd2};
        #pragma unroll
        for (int k = 0; k < 3; ++k)
            #pragma unroll
            for (int h = 0; h < 3; ++h)
                gO[k * 3 + h] = dfeat[h] * ndv[k];      // from dr_o
        #pragma unroll
        for (int h = 0; h < 3; ++h)
            #pragma unroll
            for (int l = 0; l < 3; ++l) {
                float s = 0.f;                          // from o_no
                #pragma unroll
                for (int m = 0; m < 3; ++m) s = fmaf(dfeat[6 + l * 3 + m], Nr[h * 3 + m], s);
                gO[h * 3 + l] += s;
            }
    }

    // ---- single barrier: publish psum + gradients together ----
    p_s[t] = psum;
    #pragma unroll
    for (int q = 0; q < 3; ++q) red[t][q] = gdr[q];
    #pragma unroll
    for (int q = 0; q < 9; ++q) red[t][3 + q] = gO[q];
    __syncthreads();

    // energy output
    {
        float S = 0.f;
        #pragma unroll
        for (int m = 0; m < 20; ++m) S += p_s[bl * 20 + m];
        const volatile float* fcv = ws_fc + o;
        out_energy[o] = S * fcv[0];
    }

    for (int i = t; i < 16 * 12; i += 320) {
        int bb = i / 12, q = i % 12;
        float s = 0.f;
        #pragma unroll
        for (int m = 0; m < 20; ++m) s += red[bb * 20 + m][q];
        G[bb][q] = s;
    }
    __syncthreads();

    if (t < 16) {
        const int gb = blockIdx.x * 16 + t;
        out_force[gb * 3 + 0] = G[t][0];
        out_force[gb * 3 + 1] = G[t][1];
        out_force[gb * 3 + 2] = G[t][2];
        const float* Og = orientation + (size_t)gb * 9;
        float t0 = 0.f, t1 = 0.f, t2 = 0.f;
        #pragma unroll
        for (int jj = 0; jj < 3; ++jj) {
            float u0 = G[t][3 + 0 * 3 + jj], u1 = G[t][3 + 1 * 3 + jj], u2 = G[t][3 + 2 * 3 + jj];
            float v0 = Og[0 * 3 + jj], v1 = Og[1 * 3 + jj], v2 = Og[2 * 3 + jj];
            t0 += u1 * v2 - u2 * v1;
            t1 += u2 * v0 - u0 * v2;
            t2 += u0 * v1 - u1 * v0;
        }
        out_torque[gb * 3 + 0] = t0;
        out_torque[gb * 3 + 1] = t1;
        out_torque[gb * 3 + 2] = t2;
    }
}

extern "C" void kernel_launch(void* const* d_in, const int* in_sizes, int n_in,
                              void* d_out, int out_size, void* d_ws, size_t ws_size,
                              hipStream_t stream) {
    const float* dr            = (const float*)d_in[0];
    const float* orientation   = (const float*)d_in[1];
    const float* n_orientation = (const float*)d_in[2];
    const float* W0 = (const float*)d_in[3];
    const float* b0 = (const float*)d_in[4];
    const float* W1 = (const float*)d_in[5];
    const float* b1 = (const float*)d_in[6];
    const float* W2 = (const float*)d_in[7];
    const float* b2 = (const float*)d_in[8];
    const float* f1 = (const float*)d_in[9];
    const float* f2 = (const float*)d_in[10];

    const int B = in_sizes[0] / (NB * 3);   // 32768

    float* out = (float*)d_out;
    float* out_force  = out;
    float* out_torque = out + (size_t)3 * B;
    float* out_energy = out + (size_t)6 * B;

    float* ws_R   = (float*)d_ws;                       // B*20
    float* ws_fc  = ws_R  + (size_t)B * NSEL;           // B*20
    float* ws_F   = ws_fc + (size_t)B * NSEL;           // B
    int*   ws_idx = (int*)(ws_F + B);                   // B*20
    float* ws_ndn = (float*)(ws_idx + (size_t)B * NSEL);// B*20*3
    float* ws_W0T = ws_ndn + (size_t)B * NSEL * 3;      // 960

    sel_kernel<<<B / 4, 256, 0, stream>>>(dr, W0, ws_R, ws_fc, ws_F, ws_idx, ws_ndn, ws_W0T);
    energy_kernel<<<B / 16, 320, 0, stream>>>(orientation, n_orientation,
                                              ws_W0T, b0, W1, b1, W2, b2, f1, f2,
                                              ws_R, ws_fc, ws_F, ws_idx, ws_ndn,
                                              out_force, out_torque, out_energy);
}

// Round 7
// 525.950 us; speedup vs baseline: 1.0444x; 1.0444x over previous
//
#include <hip/hip_runtime.h>

#define EPSF 1e-8f
#define RCUT 4.8f
#define NB 64
#define NSEL 20

typedef float v2f __attribute__((ext_vector_type(2)));

__device__ __forceinline__ float fast_tanh(float x) {
    float e = __expf(2.0f * x);
    return 1.0f - __fdividef(2.0f, e + 1.0f);
}

// ---------------- Kernel A: norms + select 20 nearest (sorted) ----------------
extern "C" __global__ void __launch_bounds__(256)
sel_kernel(const float* __restrict__ dr, const float* __restrict__ W0,
           float* __restrict__ ws_R, float* __restrict__ ws_fc,
           float* __restrict__ ws_F, int* __restrict__ ws_idx,
           float* __restrict__ ws_ndn, float* __restrict__ ws_W0T)
{
    __shared__ float R_s[256];
    const int t = threadIdx.x;
    const int g = t >> 6;       // which b within block (0..3)
    const int j = t & 63;       // neighbor id
    const int b = blockIdx.x * 4 + g;

    const float* p = dr + ((size_t)b * NB + j) * 3;
    float x = p[0] + EPSF, y = p[1] + EPSF, z = p[2] + EPSF;
    float R = sqrtf(x * x + y * y + z * z);
    R_s[t] = R;
    __syncthreads();

    // stable rank: count (Rk < R) or (Rk == R and k < j)
    int rank = 0;
    const float* grp = R_s + g * 64;
    #pragma unroll 8
    for (int k = 0; k < 64; ++k) {
        float Rk = grp[k];
        rank += (Rk < R || (Rk == R && k < j)) ? 1 : 0;
    }

    float fc = 0.0f;
    if (rank < NSEL) {
        fc = (R > RCUT) ? 0.0f
                        : (0.5f * __cosf(3.14159265358979323846f * R / RCUT) + 0.5f);
        size_t o = (size_t)b * NSEL + rank;
        ws_R[o]  = R;
        ws_fc[o] = fc;
        ws_idx[o] = j;
        float inv = 1.0f / R;
        ws_ndn[o * 3 + 0] = x * inv;
        ws_ndn[o * 3 + 1] = y * inv;
        ws_ndn[o * 3 + 2] = z * inv;
    }

    // F[b] = sum of selected fc over this wave (each group is exactly one wave)
    float F = fc;
    for (int off = 32; off > 0; off >>= 1) F += __shfl_xor(F, off, 64);
    if (j == 0) ws_F[b] = F;

    // one-time W0 transpose (block 0 only; A always runs before B on the stream)
    if (blockIdx.x == 0) {
        for (int i = t; i < 15 * 64; i += 256) {
            int k = i >> 6, jj = i & 63;
            ws_W0T[jj * 15 + k] = W0[i];
        }
    }
}

// ---------------- Kernel B: per-pair MLP fwd + analytic bwd ----------------
// R5 structure (best: 409us) + v_pk_fma_f32: the two 64x64 loops (layer-2 fwd
// accumulate, bwd dh1 reduction) and z3/dz2 run on float2 ext-vectors so the
// backend emits packed fp32 FMA (2 MACs/inst; gfx950 scalar FMA is only
// ~103TF of the 157TF peak -- packed is the rest).
extern "C" __global__ void __launch_bounds__(320, 4)
energy_kernel(const float* __restrict__ orientation, const float* __restrict__ n_or,
              const float* __restrict__ W0T, const float* __restrict__ b0,
              const float* __restrict__ W1, const float* __restrict__ b1,
              const float* __restrict__ W2, const float* __restrict__ b2v,
              const float* __restrict__ f1, const float* __restrict__ f2,
              const float* __restrict__ ws_R, const float* __restrict__ ws_fc,
              const float* __restrict__ ws_F, const int* __restrict__ ws_idx,
              const float* __restrict__ ws_ndn,
              float* __restrict__ out_force, float* __restrict__ out_torque,
              float* __restrict__ out_energy)
{
    __shared__ float p_s[320];
    __shared__ float red[320][12];
    __shared__ float G[16][12];

    const int t = threadIdx.x;
    const int bl = t / 20;      // local b (0..15)
    const int n  = t % 20;      // selected-neighbor slot
    const int b  = blockIdx.x * 16 + bl;
    const size_t o = (size_t)b * NSEL + n;

    // feat = [dr_o(3), dr_no(3), o_no(9)]; O/Nr/nd scoped so they die here.
    float feat[15];
    {
        const float nd0 = ws_ndn[o * 3 + 0];
        const float nd1 = ws_ndn[o * 3 + 1];
        const float nd2 = ws_ndn[o * 3 + 2];
        const int  idx = ws_idx[o];
        float O[9], Nr[9];
        const float* Op = orientation + (size_t)b * 9;
        #pragma unroll
        for (int i = 0; i < 9; ++i) O[i] = Op[i];
        const float* Np = n_or + ((size_t)b * NB + idx) * 9;
        #pragma unroll
        for (int i = 0; i < 9; ++i) Nr[i] = Np[i];

        #pragma unroll
        for (int h = 0; h < 3; ++h)
            feat[h] = nd0 * O[h] + nd1 * O[3 + h] + nd2 * O[6 + h];
        #pragma unroll
        for (int h = 0; h < 3; ++h)
            feat[3 + h] = nd0 * Nr[h] + nd1 * Nr[3 + h] + nd2 * Nr[6 + h];
        #pragma unroll
        for (int l = 0; l < 3; ++l)
            #pragma unroll
            for (int m = 0; m < 3; ++m)
                feat[6 + l * 3 + m] = O[l] * Nr[m] + O[3 + l] * Nr[3 + m] + O[6 + l] * Nr[6 + m];
    }

    // ---------- forward (j, j+1 interleaved; layer-2 in packed fp32) ----------
    v2f acc2[32];                       // z2 accumulators -> h2 -> dz2 (in place)
    {
        const v2f* b1v = (const v2f*)b1;
        #pragma unroll
        for (int i = 0; i < 32; ++i) acc2[i] = b1v[i];
    }

    for (int j = 0; j < 64; j += 2) {
        const float* w0a = W0T + j * 15;
        const float* w0b = w0a + 15;
        float za = b0[j], zb = b0[j + 1];
        #pragma unroll
        for (int k = 0; k < 15; ++k) {
            za = fmaf(feat[k], w0a[k], za);
            zb = fmaf(feat[k], w0b[k], zb);
        }
        float ha = fast_tanh(za), hb = fast_tanh(zb);
        v2f ha2 = {ha, ha}, hb2 = {hb, hb};
        const v2f* w1a = (const v2f*)(W1 + j * 64);
        const v2f* w1b = w1a + 32;
        #pragma unroll
        for (int i = 0; i < 32; ++i)
            acc2[i] = __builtin_elementwise_fma(hb2, w1b[i],
                        __builtin_elementwise_fma(ha2, w1a[i], acc2[i]));
    }

    // ---------- h2, z3 (packed partial sums) ----------
    const v2f* w2v = (const v2f*)W2;
    v2f z3v0 = {b2v[0], 0.f}, z3v1 = {0.f, 0.f};
    #pragma unroll
    for (int i = 0; i < 32; i += 2) {
        v2f h2a, h2b;
        h2a.x = fast_tanh(acc2[i].x);     h2a.y = fast_tanh(acc2[i].y);
        h2b.x = fast_tanh(acc2[i + 1].x); h2b.y = fast_tanh(acc2[i + 1].y);
        acc2[i] = h2a; acc2[i + 1] = h2b;
        z3v0 = __builtin_elementwise_fma(h2a, w2v[i],     z3v0);
        z3v1 = __builtin_elementwise_fma(h2b, w2v[i + 1], z3v1);
    }
    const float z3 = (z3v0.x + z3v0.y) + (z3v1.x + z3v1.y);
    const float enc = fast_tanh(z3);
    float x;
    {
        const volatile float* Rv = ws_R + o;    // late load: don't hold R
        x = Rv[0] - (enc * enc + EPSF);
    }

    const float lx = __logf(x);
    float psum = 0.f, csum = 0.f;
    #pragma unroll
    for (int q = 0; q < 3; ++q) {
        float aq = f1[q] * f1[q] + EPSF;
        float cq = f2[q] * f2[q] + EPSF;
        float tq = __expf(-cq * (__logf(aq) + lx));   // (a*x)^(-c)
        psum += tq;
        csum = fmaf(cq, tq, csum);
    }
    const float dpdx = -__fdividef(csum, x);

    p_s[t] = psum;
    __syncthreads();
    {
        float S = 0.f;
        for (int m = 0; m < 20; ++m) S += p_s[bl * 20 + m];
        const volatile float* fcv = ws_fc + o;  // late load: don't hold fc
        out_energy[o] = S * fcv[0];
    }

    // ---------- backward ----------
    float dz3;
    {
        const volatile float* Fv = ws_F + b;    // late load: don't hold F
        dz3 = Fv[0] * dpdx * (-2.f * enc) * (1.f - enc * enc);
    }
    {
        const v2f one2 = {1.f, 1.f};
        const v2f dz3v = {dz3, dz3};
        #pragma unroll
        for (int i = 0; i < 32; ++i) {
            v2f h2 = acc2[i];
            v2f d = one2 - h2 * h2;                 // pk fma/mul
            acc2[i] = (dz3v * w2v[i]) * d;          // dz2 (packed)
        }
    }

    float dfeat[15];
    #pragma unroll
    for (int k = 0; k < 15; ++k) dfeat[k] = 0.f;

    for (int j = 0; j < 64; j += 2) {
        const v2f* w1a = (const v2f*)(W1 + j * 64);
        const v2f* w1b = w1a + 32;
        v2f sa0 = {0.f, 0.f}, sa1 = {0.f, 0.f}, sb0 = {0.f, 0.f}, sb1 = {0.f, 0.f};
        #pragma unroll
        for (int i = 0; i < 32; i += 2) {
            sa0 = __builtin_elementwise_fma(acc2[i],     w1a[i],     sa0);
            sa1 = __builtin_elementwise_fma(acc2[i + 1], w1a[i + 1], sa1);
            sb0 = __builtin_elementwise_fma(acc2[i],     w1b[i],     sb0);
            sb1 = __builtin_elementwise_fma(acc2[i + 1], w1b[i + 1], sb1);
        }
        float dha = (sa0.x + sa0.y) + (sa1.x + sa1.y);
        float dhb = (sb0.x + sb0.y) + (sb1.x + sb1.y);
        const float* w0a = W0T + j * 15;
        const float* w0b = w0a + 15;
        float za = b0[j], zb = b0[j + 1];               // recompute h1 pair
        #pragma unroll
        for (int k = 0; k < 15; ++k) {
            za = fmaf(feat[k], w0a[k], za);
            zb = fmaf(feat[k], w0b[k], zb);
        }
        float ha = fast_tanh(za), hb = fast_tanh(zb);
        float dza = dha * (1.f - ha * ha);
        float dzb = dhb * (1.f - hb * hb);
        #pragma unroll
        for (int k = 0; k < 15; ++k)
            dfeat[k] = fmaf(dzb, w0b[k], fmaf(dza, w0a[k], dfeat[k]));
    }

    // ---- epilogue: reload O/Nr/nd (volatile: keep live ranges short above) ----
    float O[9], Nr[9], nd0, nd1, nd2;
    {
        const volatile int* iv = ws_idx + o;
        const int idx = iv[0];
        const volatile float* Ov = orientation + (size_t)b * 9;
        const volatile float* Nv = n_or + ((size_t)b * NB + idx) * 9;
        #pragma unroll
        for (int i = 0; i < 9; ++i) O[i] = Ov[i];
        #pragma unroll
        for (int i = 0; i < 9; ++i) Nr[i] = Nv[i];
        const volatile float* nv = ws_ndn + o * 3;
        nd0 = nv[0]; nd1 = nv[1]; nd2 = nv[2];
    }

    float gdr[3];
    #pragma unroll
    for (int k = 0; k < 3; ++k)
        gdr[k] = dfeat[0] * O[k * 3] + dfeat[1] * O[k * 3 + 1] + dfeat[2] * O[k * 3 + 2]
               + dfeat[3] * Nr[k * 3] + dfeat[4] * Nr[k * 3 + 1] + dfeat[5] * Nr[k * 3 + 2];

    float ndv[3] = {nd0, nd1, nd2};
    float gO[9];
    #pragma unroll
    for (int k = 0; k < 3; ++k)
        #pragma unroll
        for (int h = 0; h < 3; ++h)
            gO[k * 3 + h] = dfeat[h] * ndv[k];      // from dr_o
    #pragma unroll
    for (int h = 0; h < 3; ++h)
        #pragma unroll
        for (int l = 0; l < 3; ++l) {
            float s = 0.f;                          // from o_no
            #pragma unroll
            for (int m = 0; m < 3; ++m) s = fmaf(dfeat[6 + l * 3 + m], Nr[h * 3 + m], s);
            gO[h * 3 + l] += s;
        }

    #pragma unroll
    for (int q = 0; q < 3; ++q) red[t][q] = gdr[q];
    #pragma unroll
    for (int q = 0; q < 9; ++q) red[t][3 + q] = gO[q];
    __syncthreads();

    for (int i = t; i < 16 * 12; i += 320) {
        int bb = i / 12, q = i % 12;
        float s = 0.f;
        for (int m = 0; m < 20; ++m) s += red[bb * 20 + m][q];
        G[bb][q] = s;
    }
    __syncthreads();

    if (t < 16) {
        const int gb = blockIdx.x * 16 + t;
        out_force[gb * 3 + 0] = G[t][0];
        out_force[gb * 3 + 1] = G[t][1];
        out_force[gb * 3 + 2] = G[t][2];
        const float* Og = orientation + (size_t)gb * 9;
        float t0 = 0.f, t1 = 0.f, t2 = 0.f;
        #pragma unroll
        for (int jj = 0; jj < 3; ++jj) {
            float u0 = G[t][3 + 0 * 3 + jj], u1 = G[t][3 + 1 * 3 + jj], u2 = G[t][3 + 2 * 3 + jj];
            float v0 = Og[0 * 3 + jj], v1 = Og[1 * 3 + jj], v2 = Og[2 * 3 + jj];
            t0 += u1 * v2 - u2 * v1;
            t1 += u2 * v0 - u0 * v2;
            t2 += u0 * v1 - u1 * v0;
        }
        out_torque[gb * 3 + 0] = t0;
        out_torque[gb * 3 + 1] = t1;
        out_torque[gb * 3 + 2] = t2;
    }
}

extern "C" void kernel_launch(void* const* d_in, const int* in_sizes, int n_in,
                              void* d_out, int out_size, void* d_ws, size_t ws_size,
                              hipStream_t stream) {
    const float* dr            = (const float*)d_in[0];
    const float* orientation   = (const float*)d_in[1];
    const float* n_orientation = (const float*)d_in[2];
    const float* W0 = (const float*)d_in[3];
    const float* b0 = (const float*)d_in[4];
    const float* W1 = (const float*)d_in[5];
    const float* b1 = (const float*)d_in[6];
    const float* W2 = (const float*)d_in[7];
    const float* b2 = (const float*)d_in[8];
    const float* f1 = (const float*)d_in[9];
    const float* f2 = (const float*)d_in[10];

    const int B = in_sizes[0] / (NB * 3);   // 32768

    float* out = (float*)d_out;
    float* out_force  = out;
    float* out_torque = out + (size_t)3 * B;
    float* out_energy = out + (size_t)6 * B;

    float* ws_R   = (float*)d_ws;                       // B*20
    float* ws_fc  = ws_R  + (size_t)B * NSEL;           // B*20
    float* ws_F   = ws_fc + (size_t)B * NSEL;           // B
    int*   ws_idx = (int*)(ws_F + B);                   // B*20
    float* ws_ndn = (float*)(ws_idx + (size_t)B * NSEL);// B*20*3
    float* ws_W0T = ws_ndn + (size_t)B * NSEL * 3;      // 960

    sel_kernel<<<B / 4, 256, 0, stream>>>(dr, W0, ws_R, ws_fc, ws_F, ws_idx, ws_ndn, ws_W0T);
    energy_kernel<<<B / 16, 320, 0, stream>>>(orientation, n_orientation,
                                              ws_W0T, b0, W1, b1, W2, b2, f1, f2,
                                              ws_R, ws_fc, ws_F, ws_idx, ws_ndn,
                                              out_force, out_torque, out_energy);
}